// Round 9
// baseline (2152.605 us; speedup 1.0000x reference)
//
#include <hip/hip_runtime.h>
#include <cmath>

#ifndef M_PI
#define M_PI 3.14159265358979323846
#endif

#define T_LEN   160000
#define NSEG    155
#define ROWS    32
#define NBANDS  8

#define CHUNK   128                  // samples per barrier interval
#define NQC     32                   // float4 quads per chunk per chain
#define NCHUNK  1248                 // 128*1248 = 159744 = all samples any segment uses
#define TOT_IT  (NCHUNK + 5)         // 6-stage pipeline drain
#define LOUD_FLOATS (NBANDS * 2 * ROWS * NSEG)   // 79360
#define NPAIRS  (NBANDS * ROWS * NSEG)           // 39680

struct AllCoefs {
    float h[NBANDS][5];   // b0 b1 b2 a1 a2 (a0-normalized, f32-cast like np.float32)
    float l[NBANDS][5];
};

// Workgroup barrier without the vmcnt(0) drain (only LDS carries inter-wave
// data; w0's global prefetch stays in flight across the barrier).
__device__ __forceinline__ void barrier_lds_only() {
    asm volatile("s_waitcnt lgkmcnt(0)\n\ts_barrier" ::: "memory");
}

// ============================ Fused pipeline =============================
// R6 pipe structure UNCHANGED (verified bit-exact, steady 2041-2046 us =
// 99.9% of the dependency floor: 159744 samples x 2 dependent FMAs x
// ~15.3 cyc single-wave dependent-use latency = 2039 us).
//
// R9 = R8's fused last-block reduction with the counter-base bug fixed:
// R8 assumed the flag counter started ==0 mod 16; the harness re-poisons
// the workspace, so the block seeing (ret&15)==15 could be an EARLY
// arrival that reduced before the other blocks wrote loud (tripwire
// divergence; graph path happened to start at base 0 and was bit-exact,
// which also validated the fence/atomic cross-XCD visibility).  The host
// now zeroes the flag with hipMemsetAsync (graph-capture-legal node), so
// the winner is provably the 16th/last arrival for every replay.  Output
// bits are winner-independent: the reduce order is fixed (tid-strided
// double sum).
__global__ __launch_bounds__(384, 1)
void tf_pipe6_kernel(const float* __restrict__ sig, const float* __restrict__ wm,
                     float* __restrict__ loud, unsigned* __restrict__ flag,
                     float* __restrict__ out, AllCoefs C) {
    __shared__ float4 fA[3][NQC * 32];     // hp FIR out / hp y (48 KiB)
    __shared__ float4 fB[3][NQC * 32];     // lp FIR out / lp y (48 KiB)
    __shared__ float4 fC[2][NQC * 32];     // base weight-FIR out (32 KiB)
    __shared__ float  PS[2][2][32];        // reset-chunk x[0],x[1] per chain

    const int band = blockIdx.x;
    const int src  = blockIdx.y;              // 0 = signal, 1 = watermark
    const int tid  = threadIdx.x;
    const int wid  = tid >> 6;                // 0..5
    const int lane = tid & 63;
    const int ch   = lane & 31;               // chain = batch row

    const float hb0 = C.h[band][0], hb1 = C.h[band][1], hb2 = C.h[band][2];
    const float hna1 = -C.h[band][3], hna2 = -C.h[band][4];
    const float lb0 = C.l[band][0], lb1 = C.l[band][1], lb2 = C.l[band][2];
    const float lna1 = -C.l[band][3], lna2 = -C.l[band][4];
    const float NA1 =  1.79999995231628417969f; // -np.float32(-1.8)
    const float NA2 = -0.810000002384185791f;   // -np.float32(0.81)

    const float* __restrict__ xrow = (src ? wm : sig) + (size_t)ch * T_LEN;
    const float4* __restrict__ xq  = (const float4*)xrow;   // global quad array

    float x1 = 0.f, x2 = 0.f, y1 = 0.f, y2 = 0.f, acc = 0.f;

    float4 pfA_[16], pfB_[16];                // w0 sub-chunk ping-pong prefetch
    if (wid == 0 && lane < 32) {
        #pragma unroll
        for (int i = 0; i < 16; ++i) pfA_[i] = xq[i];   // chunk 0, sub 0
    }

// FIR halves (3 VALU) and REC halves (2 VALU) — identical arithmetic and
// order to the R4 kernel verified BIT-EXACT (absmax 0.0).
#define FH(xx, oo) { float s1_ = __fmaf_rn(hb0, xx, __fmul_rn(hb1, x1)); \
                     oo = __fmaf_rn(hb2, x2, s1_); x2 = x1; x1 = xx; }
#define RH(ff, oo) { float s3_ = __fmaf_rn(hna1, y1, ff); \
                     oo = __fmaf_rn(hna2, y2, s3_); y2 = y1; y1 = oo; }
#define FL(xx, oo) { float s1_ = __fmaf_rn(lb0, xx, __fmul_rn(lb1, x1)); \
                     oo = __fmaf_rn(lb2, x2, s1_); x2 = x1; x1 = xx; }
#define RL(ff, oo) { float s3_ = __fmaf_rn(lna1, y1, ff); \
                     oo = __fmaf_rn(lna2, y2, s3_); y2 = y1; y1 = oo; }
#define FW(xx, oo) { float s1_ = __fmaf_rn(-2.0f, x1, xx); \
                     oo = __fadd_rn(s1_, x2); x2 = x1; x1 = xx; }
#define RW(ff)     { float s3_ = __fmaf_rn(NA1, y1, ff); \
                     float yy_ = __fmaf_rn(NA2, y2, s3_); \
                     y2 = y1; y1 = yy_; acc = __fmaf_rn(yy_, yy_, acc); }

    for (int iter = 0; iter < TOT_IT; ++iter) {
        if (wid == 0) {
            // ---- FIRhp: global x -> fA[c%3] (3 VALU/sample) ----
            const int c = iter;
            if (c < NCHUNK && lane < 32) {
                float4* __restrict__ ob = fA[c % 3];
                // sub 0: consume pfA_, refill pfB_ with sub 1
                #pragma unroll
                for (int i = 0; i < 16; ++i) {
                    float4 v = pfA_[i];
                    pfB_[i] = xq[(2 * c + 1) * 16 + i];
                    float4 o;
                    FH(v.x, o.x) FH(v.y, o.y) FH(v.z, o.z) FH(v.w, o.w)
                    ob[i * 32 + ch] = o;
                }
                // sub 1: consume pfB_, refill pfA_ with next chunk's sub 0
                #pragma unroll
                for (int i = 0; i < 16; ++i) {
                    float4 v = pfB_[i];
                    pfA_[i] = xq[(2 * c + 2) * 16 + i];
                    float4 o;
                    FH(v.x, o.x) FH(v.y, o.y) FH(v.z, o.z) FH(v.w, o.w)
                    ob[(16 + i) * 32 + ch] = o;
                }
                // max prefetch: c=1247 -> quads 39936..39951 -> sample
                // 159807 < 160000 (in-bounds); loads ride across barrier
            }
        } else if (wid == 4) {
            // ---- REChp: fA[c%3] in place (2 VALU/sample) ----
            const int c = iter - 1;
            if (c >= 0 && c < NCHUNK && lane < 32) {
                float4* __restrict__ b = fA[c % 3];
                #pragma unroll
                for (int g = 0; g < 2; ++g) {
                    float4 v[16];
                    #pragma unroll
                    for (int i = 0; i < 16; ++i) v[i] = b[(g * 16 + i) * 32 + ch];
                    #pragma unroll
                    for (int i = 0; i < 16; ++i) {
                        float4 o;
                        RH(v[i].x, o.x) RH(v[i].y, o.y) RH(v[i].z, o.z) RH(v[i].w, o.w)
                        b[(g * 16 + i) * 32 + ch] = o;
                    }
                }
            }
        } else if (wid == 1) {
            // ---- FIRlp: fA[c%3] -> fB[c%3] (3 VALU/sample) ----
            const int c = iter - 2;
            if (c >= 0 && c < NCHUNK && lane < 32) {
                const float4* __restrict__ ib = fA[c % 3];
                float4* __restrict__ ob = fB[c % 3];
                #pragma unroll
                for (int g = 0; g < 2; ++g) {
                    float4 v[16];
                    #pragma unroll
                    for (int i = 0; i < 16; ++i) v[i] = ib[(g * 16 + i) * 32 + ch];
                    #pragma unroll
                    for (int i = 0; i < 16; ++i) {
                        float4 o;
                        FL(v[i].x, o.x) FL(v[i].y, o.y) FL(v[i].z, o.z) FL(v[i].w, o.w)
                        ob[(g * 16 + i) * 32 + ch] = o;
                    }
                }
            }
        } else if (wid == 5) {
            // ---- REClp: fB[c%3] in place (2 VALU/sample) ----
            const int c = iter - 3;
            if (c >= 0 && c < NCHUNK && lane < 32) {
                float4* __restrict__ b = fB[c % 3];
                #pragma unroll
                for (int g = 0; g < 2; ++g) {
                    float4 v[16];
                    #pragma unroll
                    for (int i = 0; i < 16; ++i) v[i] = b[(g * 16 + i) * 32 + ch];
                    #pragma unroll
                    for (int i = 0; i < 16; ++i) {
                        float4 o;
                        RL(v[i].x, o.x) RL(v[i].y, o.y) RL(v[i].z, o.z) RL(v[i].w, o.w)
                        b[(g * 16 + i) * 32 + ch] = o;
                    }
                }
            }
        } else if (wid == 2) {
            // ---- FIRwB: fB[c%3] -> fC[c%2], base weight FIR, no resets ----
            const int c = iter - 4;
            if (c >= 0 && c < NCHUNK && lane < 32) {
                const float4* __restrict__ ib = fB[c % 3];
                float4* __restrict__ ob = fC[c & 1];
                #pragma unroll
                for (int g = 0; g < 2; ++g) {
                    float4 v[16];
                    #pragma unroll
                    for (int i = 0; i < 16; ++i) v[i] = ib[(g * 16 + i) * 32 + ch];
                    if (g == 0 && (c & 7) == 0) {
                        // stash raw x[0],x[1] for RECw's reset patch
                        PS[c & 1][0][ch] = v[0].x;
                        PS[c & 1][1][ch] = v[0].y;
                    }
                    #pragma unroll
                    for (int i = 0; i < 16; ++i) {
                        float4 o;
                        FW(v[i].x, o.x) FW(v[i].y, o.y) FW(v[i].z, o.z) FW(v[i].w, o.w)
                        ob[(g * 16 + i) * 32 + ch] = o;
                    }
                }
            }
        } else {
            // ---- RECw: fC[c%2] -> loud, 64-lane dual parity ----
            const int c = iter - 5;
            if (c >= 0 && c < NCHUNK) {
                const bool EVh = (lane < 32);     // lanes 0-31 even segs
                const float4* __restrict__ ib = fC[c & 1];
                const float ps0 = PS[c & 1][0][ch];
                const float ps1 = PS[c & 1][1][ch];
                const bool rst = ((c & 15) == (EVh ? 0 : 8)) && ((c >> 3) < NSEG);
                if (rst) { y1 = 0.f; y2 = 0.f; acc = 0.f; }
                #pragma unroll
                for (int g = 0; g < 2; ++g) {
                    float4 v[16];
                    #pragma unroll
                    for (int i = 0; i < 16; ++i) v[i] = ib[(g * 16 + i) * 32 + ch];
                    if (g == 0 && rst) {
                        // exact reference reset path: f0=x0, f1=fma(-2,x0,x1)
                        v[0].x = ps0;
                        v[0].y = __fmaf_rn(-2.0f, ps0, ps1);
                    }
                    #pragma unroll
                    for (int i = 0; i < 16; ++i) {
                        RW(v[i].x) RW(v[i].y) RW(v[i].z) RW(v[i].w)
                    }
                }
                const bool endf = ((c & 15) == (EVh ? 15 : 7)) && (c >= 15);
                if (endf) {
                    const int j = (c - 15) >> 3;
                    float e = __fmul_rn(acc, 0.00048828125f);   // /2048 exact
                    loud[((size_t)((band * 2 + src) * ROWS + ch)) * NSEG + j] =
                        __fmul_rn(10.0f, log10f(__fadd_rn(e, 1e-8f)));
                }
            }
        }
        barrier_lds_only();
    }
#undef FH
#undef RH
#undef FL
#undef RL
#undef FW
#undef RW

    // ==================== fused last-block reduction ====================
    // flag is hipMemsetAsync'd to 0 before every launch, so arrivals are
    // 0..15 and ret==15 identifies the LAST block (all loud writes released
    // by the 15 prior fences + this block's own).
    __syncthreads();                       // all loud stores of this block done
    __shared__ int sWin;
    if (tid == 0) {
        __threadfence();                   // release this block's loud writes
        unsigned ret = atomicAdd(flag, 1u);   // device-scope
        sWin = (ret == 15u) ? 1 : 0;          // 16th (last) arrival
    }
    __syncthreads();
    if (sWin) {
        __threadfence();                   // acquire all blocks' loud writes
        __shared__ double sh[256];
        const int per_band = ROWS * NSEG;  // 4960
        if (tid < 256) {
            double s = 0.0;
            for (int idx = tid; idx < NPAIRS; idx += 256) {
                int b  = idx / per_band;
                int rs = idx - b * per_band;
                float a = loud[(size_t)(b * 2 + 0) * per_band + rs];
                float w = loud[(size_t)(b * 2 + 1) * per_band + rs];
                s += fabs((double)w - (double)a);
            }
            sh[tid] = s;
        }
        __syncthreads();
        for (int off = 128; off > 0; off >>= 1) {
            if (tid < off) sh[tid] += sh[tid + off];
            __syncthreads();
        }
        if (tid == 0) out[0] = (float)(sh[0] / (double)NPAIRS);
    }
}

// Host-side coefficients: f64 with the reference's exact expression order,
// then cast each to f32 (mirrors tuple(np.float32(v / a0) ...)).
static void mk_hp(double cutoff, float* o) {
    const double w0    = 2.0 * M_PI * cutoff / 16000.0;
    const double alpha = sin(w0) / (2.0 * 0.707);
    const double cw    = cos(w0);
    const double b0 = (1.0 + cw) / 2.0;
    const double b1 = -(1.0 + cw);
    const double b2 = (1.0 + cw) / 2.0;
    const double a0 = 1.0 + alpha;
    const double a1 = -2.0 * cw;
    const double a2 = 1.0 - alpha;
    o[0] = (float)(b0 / a0); o[1] = (float)(b1 / a0); o[2] = (float)(b2 / a0);
    o[3] = (float)(a1 / a0); o[4] = (float)(a2 / a0);
}

static void mk_lp(double cutoff, float* o) {
    const double w0    = 2.0 * M_PI * cutoff / 16000.0;
    const double alpha = sin(w0) / (2.0 * 0.707);
    const double cw    = cos(w0);
    const double b0 = (1.0 - cw) / 2.0;
    const double b1 = 1.0 - cw;
    const double b2 = (1.0 - cw) / 2.0;
    const double a0 = 1.0 + alpha;
    const double a1 = -2.0 * cw;
    const double a2 = 1.0 - alpha;
    o[0] = (float)(b0 / a0); o[1] = (float)(b1 / a0); o[2] = (float)(b2 / a0);
    o[3] = (float)(a1 / a0); o[4] = (float)(a2 / a0);
}

extern "C" void kernel_launch(void* const* d_in, const int* in_sizes, int n_in,
                              void* d_out, int out_size, void* d_ws, size_t ws_size,
                              hipStream_t stream) {
    const float* sig = (const float*)d_in[0];
    const float* wm  = (const float*)d_in[1];
    float*    loud = (float*)d_ws;                                  // 310 KiB
    unsigned* flag = (unsigned*)((char*)d_ws + (size_t)LOUD_FLOATS * 4);

    AllCoefs C;
    for (int i = 0; i < NBANDS; ++i) {
        mk_hp(1000.0 * (double)i,       C.h[i]);   // low_cut  = i*1000 exactly
        mk_lp(1000.0 * (double)(i + 1), C.l[i]);   // high_cut = (i+1)*1000 exactly
    }

    // Zero the arrival counter (graph-capturable memset node): winner
    // selection must not depend on the poisoned workspace state.
    hipMemsetAsync(flag, 0, sizeof(unsigned), stream);

    tf_pipe6_kernel<<<dim3(NBANDS, 2), 384, 0, stream>>>(
        sig, wm, loud, flag, (float*)d_out, C);
}

// Round 10
// 2109.507 us; speedup vs baseline: 1.0204x; 1.0204x over previous
//
#include <hip/hip_runtime.h>
#include <cmath>

#ifndef M_PI
#define M_PI 3.14159265358979323846
#endif

#define T_LEN   160000
#define NSEG    155
#define ROWS    32
#define NBANDS  8

#define CHUNK   128                  // samples per barrier interval
#define NQC     32                   // float4 quads per chunk per chain
#define NCHUNK  1248                 // 128*1248 = 159744 = all samples any segment uses
#define TOT_IT  (NCHUNK + 5)         // 6-stage pipeline drain
#define LOUD_FLOATS (NBANDS * 2 * ROWS * NSEG)   // 79360
#define NPART   64                   // reduce partial blocks

struct AllCoefs {
    float h[NBANDS][5];   // b0 b1 b2 a1 a2 (a0-normalized, f32-cast like np.float32)
    float l[NBANDS][5];
};

// Workgroup barrier without the vmcnt(0) drain (only LDS carries inter-wave
// data; w0's global prefetch stays in flight across the barrier).
__device__ __forceinline__ void barrier_lds_only() {
    asm volatile("s_waitcnt lgkmcnt(0)\n\ts_barrier" ::: "memory");
}

// ============================ Fused pipeline =============================
// FINAL (R10 = R7, the session optimum: dur 2106.9 us, absmax 0.0).
// Measured law across R0-R6: pace = 31 cyc/sample invariant to wave count,
// chunk size, ILP, prefetch = the recurrence's 2 dependent FMAs/sample at
// single-wave dependent-use latency ~15.3 cyc.  Floor: 159744 x 2 x 15.3
// / 2.4GHz = 2039 us; this kernel measures 2041-2046 -> AT the floor.
// Bit-exactness is mandatory (band-0 hp is marginally stable: double pole
// at z=1), which forbids reassociation/lookahead/scan reformulations.
// R9's fused last-block reduce was tried and is SLOWER (+45 us/dispatch:
// winner's serial re-read + fence drain inside the timed kernel); the
// 64-block partial + finalize tail (R7) is the best verified ending.
__global__ __launch_bounds__(384, 1)
void tf_pipe6_kernel(const float* __restrict__ sig, const float* __restrict__ wm,
                     float* __restrict__ loud, AllCoefs C) {
    __shared__ float4 fA[3][NQC * 32];     // hp FIR out / hp y (48 KiB)
    __shared__ float4 fB[3][NQC * 32];     // lp FIR out / lp y (48 KiB)
    __shared__ float4 fC[2][NQC * 32];     // base weight-FIR out (32 KiB)
    __shared__ float  PS[2][2][32];        // reset-chunk x[0],x[1] per chain

    const int band = blockIdx.x;
    const int src  = blockIdx.y;              // 0 = signal, 1 = watermark
    const int tid  = threadIdx.x;
    const int wid  = tid >> 6;                // 0..5
    const int lane = tid & 63;
    const int ch   = lane & 31;               // chain = batch row

    const float hb0 = C.h[band][0], hb1 = C.h[band][1], hb2 = C.h[band][2];
    const float hna1 = -C.h[band][3], hna2 = -C.h[band][4];
    const float lb0 = C.l[band][0], lb1 = C.l[band][1], lb2 = C.l[band][2];
    const float lna1 = -C.l[band][3], lna2 = -C.l[band][4];
    const float NA1 =  1.79999995231628417969f; // -np.float32(-1.8)
    const float NA2 = -0.810000002384185791f;   // -np.float32(0.81)

    const float* __restrict__ xrow = (src ? wm : sig) + (size_t)ch * T_LEN;
    const float4* __restrict__ xq  = (const float4*)xrow;   // global quad array

    float x1 = 0.f, x2 = 0.f, y1 = 0.f, y2 = 0.f, acc = 0.f;

    float4 pfA_[16], pfB_[16];                // w0 sub-chunk ping-pong prefetch
    if (wid == 0 && lane < 32) {
        #pragma unroll
        for (int i = 0; i < 16; ++i) pfA_[i] = xq[i];   // chunk 0, sub 0
    }

// FIR halves (3 VALU) and REC halves (2 VALU) — identical arithmetic and
// order to the R4 kernel verified BIT-EXACT (absmax 0.0).
#define FH(xx, oo) { float s1_ = __fmaf_rn(hb0, xx, __fmul_rn(hb1, x1)); \
                     oo = __fmaf_rn(hb2, x2, s1_); x2 = x1; x1 = xx; }
#define RH(ff, oo) { float s3_ = __fmaf_rn(hna1, y1, ff); \
                     oo = __fmaf_rn(hna2, y2, s3_); y2 = y1; y1 = oo; }
#define FL(xx, oo) { float s1_ = __fmaf_rn(lb0, xx, __fmul_rn(lb1, x1)); \
                     oo = __fmaf_rn(lb2, x2, s1_); x2 = x1; x1 = xx; }
#define RL(ff, oo) { float s3_ = __fmaf_rn(lna1, y1, ff); \
                     oo = __fmaf_rn(lna2, y2, s3_); y2 = y1; y1 = oo; }
#define FW(xx, oo) { float s1_ = __fmaf_rn(-2.0f, x1, xx); \
                     oo = __fadd_rn(s1_, x2); x2 = x1; x1 = xx; }
#define RW(ff)     { float s3_ = __fmaf_rn(NA1, y1, ff); \
                     float yy_ = __fmaf_rn(NA2, y2, s3_); \
                     y2 = y1; y1 = yy_; acc = __fmaf_rn(yy_, yy_, acc); }

    for (int iter = 0; iter < TOT_IT; ++iter) {
        if (wid == 0) {
            // ---- FIRhp: global x -> fA[c%3] (3 VALU/sample) ----
            const int c = iter;
            if (c < NCHUNK && lane < 32) {
                float4* __restrict__ ob = fA[c % 3];
                // sub 0: consume pfA_, refill pfB_ with sub 1
                #pragma unroll
                for (int i = 0; i < 16; ++i) {
                    float4 v = pfA_[i];
                    pfB_[i] = xq[(2 * c + 1) * 16 + i];
                    float4 o;
                    FH(v.x, o.x) FH(v.y, o.y) FH(v.z, o.z) FH(v.w, o.w)
                    ob[i * 32 + ch] = o;
                }
                // sub 1: consume pfB_, refill pfA_ with next chunk's sub 0
                #pragma unroll
                for (int i = 0; i < 16; ++i) {
                    float4 v = pfB_[i];
                    pfA_[i] = xq[(2 * c + 2) * 16 + i];
                    float4 o;
                    FH(v.x, o.x) FH(v.y, o.y) FH(v.z, o.z) FH(v.w, o.w)
                    ob[(16 + i) * 32 + ch] = o;
                }
                // max prefetch: c=1247 -> quads 39936..39951 -> sample
                // 159807 < 160000 (in-bounds); loads ride across barrier
            }
        } else if (wid == 4) {
            // ---- REChp: fA[c%3] in place (2 VALU/sample) ----
            const int c = iter - 1;
            if (c >= 0 && c < NCHUNK && lane < 32) {
                float4* __restrict__ b = fA[c % 3];
                #pragma unroll
                for (int g = 0; g < 2; ++g) {
                    float4 v[16];
                    #pragma unroll
                    for (int i = 0; i < 16; ++i) v[i] = b[(g * 16 + i) * 32 + ch];
                    #pragma unroll
                    for (int i = 0; i < 16; ++i) {
                        float4 o;
                        RH(v[i].x, o.x) RH(v[i].y, o.y) RH(v[i].z, o.z) RH(v[i].w, o.w)
                        b[(g * 16 + i) * 32 + ch] = o;
                    }
                }
            }
        } else if (wid == 1) {
            // ---- FIRlp: fA[c%3] -> fB[c%3] (3 VALU/sample) ----
            const int c = iter - 2;
            if (c >= 0 && c < NCHUNK && lane < 32) {
                const float4* __restrict__ ib = fA[c % 3];
                float4* __restrict__ ob = fB[c % 3];
                #pragma unroll
                for (int g = 0; g < 2; ++g) {
                    float4 v[16];
                    #pragma unroll
                    for (int i = 0; i < 16; ++i) v[i] = ib[(g * 16 + i) * 32 + ch];
                    #pragma unroll
                    for (int i = 0; i < 16; ++i) {
                        float4 o;
                        FL(v[i].x, o.x) FL(v[i].y, o.y) FL(v[i].z, o.z) FL(v[i].w, o.w)
                        ob[(g * 16 + i) * 32 + ch] = o;
                    }
                }
            }
        } else if (wid == 5) {
            // ---- REClp: fB[c%3] in place (2 VALU/sample) ----
            const int c = iter - 3;
            if (c >= 0 && c < NCHUNK && lane < 32) {
                float4* __restrict__ b = fB[c % 3];
                #pragma unroll
                for (int g = 0; g < 2; ++g) {
                    float4 v[16];
                    #pragma unroll
                    for (int i = 0; i < 16; ++i) v[i] = b[(g * 16 + i) * 32 + ch];
                    #pragma unroll
                    for (int i = 0; i < 16; ++i) {
                        float4 o;
                        RL(v[i].x, o.x) RL(v[i].y, o.y) RL(v[i].z, o.z) RL(v[i].w, o.w)
                        b[(g * 16 + i) * 32 + ch] = o;
                    }
                }
            }
        } else if (wid == 2) {
            // ---- FIRwB: fB[c%3] -> fC[c%2], base weight FIR, no resets ----
            const int c = iter - 4;
            if (c >= 0 && c < NCHUNK && lane < 32) {
                const float4* __restrict__ ib = fB[c % 3];
                float4* __restrict__ ob = fC[c & 1];
                #pragma unroll
                for (int g = 0; g < 2; ++g) {
                    float4 v[16];
                    #pragma unroll
                    for (int i = 0; i < 16; ++i) v[i] = ib[(g * 16 + i) * 32 + ch];
                    if (g == 0 && (c & 7) == 0) {
                        // stash raw x[0],x[1] for RECw's reset patch
                        PS[c & 1][0][ch] = v[0].x;
                        PS[c & 1][1][ch] = v[0].y;
                    }
                    #pragma unroll
                    for (int i = 0; i < 16; ++i) {
                        float4 o;
                        FW(v[i].x, o.x) FW(v[i].y, o.y) FW(v[i].z, o.z) FW(v[i].w, o.w)
                        ob[(g * 16 + i) * 32 + ch] = o;
                    }
                }
            }
        } else {
            // ---- RECw: fC[c%2] -> loud, 64-lane dual parity ----
            const int c = iter - 5;
            if (c >= 0 && c < NCHUNK) {
                const bool EVh = (lane < 32);     // lanes 0-31 even segs
                const float4* __restrict__ ib = fC[c & 1];
                const float ps0 = PS[c & 1][0][ch];
                const float ps1 = PS[c & 1][1][ch];
                const bool rst = ((c & 15) == (EVh ? 0 : 8)) && ((c >> 3) < NSEG);
                if (rst) { y1 = 0.f; y2 = 0.f; acc = 0.f; }
                #pragma unroll
                for (int g = 0; g < 2; ++g) {
                    float4 v[16];
                    #pragma unroll
                    for (int i = 0; i < 16; ++i) v[i] = ib[(g * 16 + i) * 32 + ch];
                    if (g == 0 && rst) {
                        // exact reference reset path: f0=x0, f1=fma(-2,x0,x1)
                        v[0].x = ps0;
                        v[0].y = __fmaf_rn(-2.0f, ps0, ps1);
                    }
                    #pragma unroll
                    for (int i = 0; i < 16; ++i) {
                        RW(v[i].x) RW(v[i].y) RW(v[i].z) RW(v[i].w)
                    }
                }
                const bool endf = ((c & 15) == (EVh ? 15 : 7)) && (c >= 15);
                if (endf) {
                    const int j = (c - 15) >> 3;
                    float e = __fmul_rn(acc, 0.00048828125f);   // /2048 exact
                    loud[((size_t)((band * 2 + src) * ROWS + ch)) * NSEG + j] =
                        __fmul_rn(10.0f, log10f(__fadd_rn(e, 1e-8f)));
                }
            }
        }
        barrier_lds_only();
    }
#undef FH
#undef RH
#undef FL
#undef RL
#undef FW
#undef RW
}

// ======================================================================
// Parallelized reduction (R7).  Double-accumulation in ANY partition order
// rounds to the same f32 as the single-block version (which matched JAX
// bit-for-bit, absmax 0.0), so 64 partials + a tree finalize is
// rounding-safe.
// ======================================================================
__global__ __launch_bounds__(256)
void tf_reduce_part(const float* __restrict__ loud, double* __restrict__ part) {
    __shared__ double sh[256];
    const int per_band = ROWS * NSEG;       // 4960
    const int npairs   = NBANDS * per_band; // 39680
    double s = 0.0;
    for (int idx = blockIdx.x * 256 + threadIdx.x; idx < npairs; idx += NPART * 256) {
        int band = idx / per_band;
        int rs   = idx - band * per_band;
        float a = loud[(size_t)(band * 2 + 0) * per_band + rs];
        float b = loud[(size_t)(band * 2 + 1) * per_band + rs];
        s += fabs((double)b - (double)a);
    }
    sh[threadIdx.x] = s;
    __syncthreads();
    for (int off = 128; off > 0; off >>= 1) {
        if (threadIdx.x < off) sh[threadIdx.x] += sh[threadIdx.x + off];
        __syncthreads();
    }
    if (threadIdx.x == 0) part[blockIdx.x] = sh[0];
}

__global__ __launch_bounds__(64)
void tf_reduce_fin(const double* __restrict__ part, float* __restrict__ out) {
    __shared__ double sh[64];
    sh[threadIdx.x] = part[threadIdx.x];
    __syncthreads();
    for (int off = 32; off > 0; off >>= 1) {
        if (threadIdx.x < off) sh[threadIdx.x] += sh[threadIdx.x + off];
        __syncthreads();
    }
    if (threadIdx.x == 0)
        out[0] = (float)(sh[0] / (double)(NBANDS * ROWS * NSEG));
}

// Host-side coefficients: f64 with the reference's exact expression order,
// then cast each to f32 (mirrors tuple(np.float32(v / a0) ...)).
static void mk_hp(double cutoff, float* o) {
    const double w0    = 2.0 * M_PI * cutoff / 16000.0;
    const double alpha = sin(w0) / (2.0 * 0.707);
    const double cw    = cos(w0);
    const double b0 = (1.0 + cw) / 2.0;
    const double b1 = -(1.0 + cw);
    const double b2 = (1.0 + cw) / 2.0;
    const double a0 = 1.0 + alpha;
    const double a1 = -2.0 * cw;
    const double a2 = 1.0 - alpha;
    o[0] = (float)(b0 / a0); o[1] = (float)(b1 / a0); o[2] = (float)(b2 / a0);
    o[3] = (float)(a1 / a0); o[4] = (float)(a2 / a0);
}

static void mk_lp(double cutoff, float* o) {
    const double w0    = 2.0 * M_PI * cutoff / 16000.0;
    const double alpha = sin(w0) / (2.0 * 0.707);
    const double cw    = cos(w0);
    const double b0 = (1.0 - cw) / 2.0;
    const double b1 = 1.0 - cw;
    const double b2 = (1.0 - cw) / 2.0;
    const double a0 = 1.0 + alpha;
    const double a1 = -2.0 * cw;
    const double a2 = 1.0 - alpha;
    o[0] = (float)(b0 / a0); o[1] = (float)(b1 / a0); o[2] = (float)(b2 / a0);
    o[3] = (float)(a1 / a0); o[4] = (float)(a2 / a0);
}

extern "C" void kernel_launch(void* const* d_in, const int* in_sizes, int n_in,
                              void* d_out, int out_size, void* d_ws, size_t ws_size,
                              hipStream_t stream) {
    const float* sig = (const float*)d_in[0];
    const float* wm  = (const float*)d_in[1];
    float*  loud = (float*)d_ws;                       // 79360 floats = 310 KiB
    double* part = (double*)((char*)d_ws + (size_t)LOUD_FLOATS * 4);  // 8B-aligned

    AllCoefs C;
    for (int i = 0; i < NBANDS; ++i) {
        mk_hp(1000.0 * (double)i,       C.h[i]);   // low_cut  = i*1000 exactly
        mk_lp(1000.0 * (double)(i + 1), C.l[i]);   // high_cut = (i+1)*1000 exactly
    }

    tf_pipe6_kernel<<<dim3(NBANDS, 2), 384, 0, stream>>>(sig, wm, loud, C);
    tf_reduce_part<<<NPART, 256, 0, stream>>>(loud, part);
    tf_reduce_fin<<<1, 64, 0, stream>>>(part, (float*)d_out);
}